// Round 1
// baseline (217.311 us; speedup 1.0000x reference)
//
#include <hip/hip_runtime.h>
#include <math.h>

#define N_TOK 8192
#define DIM   4096
#define NE    16
#define TOKS  (2*N_TOK)        // 16384
#define NCHUNK (TOKS/64)       // 256
#define D4    (DIM/4)          // 1024 float4 per row
#define NSEGG 8                // D seg-groups (512 cols each); part combine depth
#define SLICEF4 128            // float4 per block slice (512 cols)
#define RPB   128              // rows per block (2 per lane)

// d_out layout (all float32):
// [0] l_aux | [1..16384] token_pos_after | [16385..32768] token_pos_before
// [32769..32784] expert_token_count | [32785..49168] weight
#define OUT_LAUX 0
#define OUT_TPA  1
#define OUT_TPB  (1+TOKS)
#define OUT_CNT  (1+2*TOKS)
#define OUT_W    (1+2*TOKS+NE)

// K1 v2: two rows per lane. 512 blocks x 256 threads.
// Block = 128 rows x one 512-col slice (g = blockIdx&7). Wave w covers the
// 128-col quarter w of the slice; lane handles rows (rg*128+lane) and +64.
// Rationale: each wave-uniform ds_read_b128 of Wg returns 1 KiB over the
// ~85 B/cyc LDS return bus (~12 cyc) regardless of broadcast; feeding TWO
// rows per read halves per-CU LDS-pipe cycles (8192->4096 instrs) and drops
// the LDS pipe below the HBM floor. x/part traffic and FMA count unchanged.
// Wg slice (32 KB) and the combine buffer (33 KB) are unioned: Wg is dead
// before the combine phase; padded pl stride (129) kills write conflicts.
__global__ __launch_bounds__(256) void k1_rowlane(
    const float4* __restrict__ x4, const float4* __restrict__ wg4,
    float* __restrict__ part)
{
    __shared__ union {
        float4 wgl[NE][SLICEF4];     // 32 KB  [e][slice f4]
        float  pl[4][NE][RPB + 1];   // 33 KB  [wave][e][row], padded
    } sm;

    const int tid  = threadIdx.x;
    const int lane = tid & 63;
    const int w    = tid >> 6;            // 0..3
    const int g    = blockIdx.x & 7;      // slice group (512 cols)
    const int rg   = blockIdx.x >> 3;     // row group (128 rows), 0..63

    // ---- stage Wg slice: 2048 float4, 8 per thread, coalesced ----
    #pragma unroll
    for (int i = 0; i < 8; ++i) {
        const int idx = i * 256 + tid;
        const int e = idx >> 7, c = idx & 127;
        sm.wgl[e][c] = wg4[(size_t)e * D4 + g * SLICEF4 + c];
    }
    __syncthreads();

    const int row0 = rg * RPB + lane;                 // and row0 + 64
    const float4* xrowA = x4 + (size_t)row0 * D4 + g * SLICEF4 + w * 32;
    const float4* xrowB = xrowA + (size_t)64 * D4;

    float accA[NE], accB[NE];
    #pragma unroll
    for (int e = 0; e < NE; ++e) { accA[e] = 0.f; accB[e] = 0.f; }

    #pragma unroll
    for (int si = 0; si < 4; ++si) {
        float4 xa[8], xb[8];
        #pragma unroll
        for (int k = 0; k < 8; ++k) {
            xa[k] = xrowA[si * 8 + k];
            xb[k] = xrowB[si * 8 + k];
        }
        #pragma unroll
        for (int e = 0; e < NE; ++e) {
            float a = accA[e], b = accB[e];
            #pragma unroll
            for (int k = 0; k < 8; ++k) {
                const float4 wv = sm.wgl[e][w * 32 + si * 8 + k]; // uniform -> broadcast
                a = fmaf(xa[k].x, wv.x, a);
                a = fmaf(xa[k].y, wv.y, a);
                a = fmaf(xa[k].z, wv.z, a);
                a = fmaf(xa[k].w, wv.w, a);
                b = fmaf(xb[k].x, wv.x, b);
                b = fmaf(xb[k].y, wv.y, b);
                b = fmaf(xb[k].z, wv.z, b);
                b = fmaf(xb[k].w, wv.w, b);
            }
            accA[e] = a; accB[e] = b;
        }
    }

    // ---- combine the 4 waves' quarter-slices through LDS ----
    __syncthreads();   // wgl reads done everywhere before pl aliases it
    #pragma unroll
    for (int e = 0; e < NE; ++e) {
        sm.pl[w][e][lane]      = accA[e];   // lane-contiguous: conflict-free
        sm.pl[w][e][64 + lane] = accB[e];
    }
    __syncthreads();

    // 2048 sums; 8 per thread; output contiguous per block (coalesced)
    #pragma unroll
    for (int j = 0; j < 8; ++j) {
        const int flat = j * 256 + tid;       // = r*16 + e, r in [0,128)
        const int r = flat >> 4, e = flat & 15;
        const float s = sm.pl[0][e][r] + sm.pl[1][e][r]
                      + sm.pl[2][e][r] + sm.pl[3][e][r];
        part[(size_t)g * (N_TOK * NE) + (size_t)rg * (RPB * NE) + flat] = s;
    }
}

// K2: combine 8 slice partials (fixed order -> deterministic), top-2, softmax,
// weights, me partials, stable intra-chunk ranks + chunk histograms.
// 128 blocks x 64 threads, one thread per row. Block = one 64-row chunk.
__global__ __launch_bounds__(64) void k2_route(
    const float* __restrict__ part, int* __restrict__ pr,
    int* __restrict__ hist, float* __restrict__ me_part,
    float* __restrict__ out)
{
    const int row   = blockIdx.x * 64 + threadIdx.x;
    const int lane  = threadIdx.x & 63;
    const int gwave = row >> 6;   // chunk index for top-1 half, in [0,128)

    float lg[NE];
    #pragma unroll
    for (int e = 0; e < NE; ++e) lg[e] = 0.f;
    const float4* p4 = (const float4*)part;
    #pragma unroll
    for (int s = 0; s < NSEGG; ++s) {
        const size_t base = ((size_t)s * N_TOK + row) * 4;
        #pragma unroll
        for (int q = 0; q < 4; ++q) {
            float4 t = p4[base + q];
            lg[q * 4 + 0] += t.x;
            lg[q * 4 + 1] += t.y;
            lg[q * 4 + 2] += t.z;
            lg[q * 4 + 3] += t.w;
        }
    }

    // top-2; strict > keeps lowest index on ties (matches lax.top_k)
    float m1 = -INFINITY; int i1 = 0;
    #pragma unroll
    for (int e = 0; e < NE; ++e)
        if (lg[e] > m1) { m1 = lg[e]; i1 = e; }
    float m2 = -INFINITY; int i2 = 0;
    #pragma unroll
    for (int e = 0; e < NE; ++e)
        if (e != i1 && lg[e] > m2) { m2 = lg[e]; i2 = e; }

    float ssum = 0.f, ex[NE];
    #pragma unroll
    for (int e = 0; e < NE; ++e) { ex[e] = __expf(lg[e] - m1); ssum += ex[e]; }
    const float inv = 1.f / ssum;

    const float e2v = __expf(m2 - m1);
    const float w1  = 1.f / (1.f + e2v);
    out[OUT_W + row]         = w1;
    out[OUT_W + N_TOK + row] = 1.f - w1;

    // per-wave me partial: butterfly each expert; lane e keeps expert e's sum
    float mymev = 0.f;
    #pragma unroll
    for (int e = 0; e < NE; ++e) {
        float mv = ex[e] * inv;
        mv += __shfl_xor(mv, 32); mv += __shfl_xor(mv, 16);
        mv += __shfl_xor(mv, 8);  mv += __shfl_xor(mv, 4);
        mv += __shfl_xor(mv, 2);  mv += __shfl_xor(mv, 1);
        if (lane == e) mymev = mv;
    }
    if (lane < NE) me_part[gwave * NE + lane] = mymev;

    // stable intra-chunk ranks + chunk histograms via ballot
    const unsigned long long mlt = (1ull << lane) - 1ull;
    int rk1 = 0, rk2 = 0;
    #pragma unroll
    for (int eo = 0; eo < NE; ++eo) {
        unsigned long long mA = __ballot(i1 == eo);
        unsigned long long mB = __ballot(i2 == eo);
        if (i1 == eo) rk1 = (int)__popcll(mA & mlt);
        if (i2 == eo) rk2 = (int)__popcll(mB & mlt);
        if (lane == eo) {
            hist[gwave * NE + eo]                = (int)__popcll(mA);
            hist[(NCHUNK / 2 + gwave) * NE + eo] = (int)__popcll(mB);
        }
    }
    pr[row]         = i1 | (rk1 << 8);
    pr[N_TOK + row] = i2 | (rk2 << 8);
}

// K3: 64 blocks x 256. Every block redundantly scans the 256x16 chunk
// histogram in LDS, then places its 256 tokens. Block 0 adds l_aux + counts.
__global__ __launch_bounds__(256) void k3_place(
    const int* __restrict__ pr, const int* __restrict__ hist,
    const float* __restrict__ me_part, float* __restrict__ out)
{
    __shared__ int   sh[NCHUNK][20];   // padded
    __shared__ int   cnt_sh[NE], ce_sh[NE];
    __shared__ float me_sh[16][17];
    __shared__ float me_tot[NE];

    const int t = threadIdx.x;

    int h[NE];
    {
        const int4* h4 = (const int4*)(hist + t * NE);
        int4 a = h4[0], b = h4[1], c = h4[2], d = h4[3];
        h[0]=a.x; h[1]=a.y; h[2]=a.z; h[3]=a.w;
        h[4]=b.x; h[5]=b.y; h[6]=b.z; h[7]=b.w;
        h[8]=c.x; h[9]=c.y; h[10]=c.z; h[11]=c.w;
        h[12]=d.x; h[13]=d.y; h[14]=d.z; h[15]=d.w;
    }
    #pragma unroll
    for (int e = 0; e < NE; ++e) sh[t][e] = h[e];
    __syncthreads();

    for (int off = 1; off < NCHUNK; off <<= 1) {
        int tmp[NE];
        #pragma unroll
        for (int e = 0; e < NE; ++e) tmp[e] = (t >= off) ? sh[t - off][e] : 0;
        __syncthreads();
        #pragma unroll
        for (int e = 0; e < NE; ++e) sh[t][e] += tmp[e];
        __syncthreads();
    }

    if (t == NCHUNK - 1) {
        #pragma unroll
        for (int e = 0; e < NE; ++e) cnt_sh[e] = sh[t][e];
    }
    if (t == NCHUNK / 2 - 1) {
        #pragma unroll
        for (int e = 0; e < NE; ++e) ce_sh[e] = sh[t][e];  // top-1 totals
    }

    int ex[NE];
    #pragma unroll
    for (int e = 0; e < NE; ++e) ex[e] = sh[t][e] - h[e];
    __syncthreads();
    #pragma unroll
    for (int e = 0; e < NE; ++e) sh[t][e] = ex[e];
    __syncthreads();

    int offs[NE];
    {
        int run = 0;
        #pragma unroll
        for (int e = 0; e < NE; ++e) { offs[e] = run; run += cnt_sh[e]; }
    }

    {
        const int tk = blockIdx.x * 256 + t;
        const int v  = pr[tk];
        const int e  = v & 255;
        const int rk = v >> 8;
        const int c  = tk >> 6;
        const int pos = sh[c][e] + offs[e] + rk;
        out[OUT_TPA + tk]  = (float)pos;
        out[OUT_TPB + pos] = (float)tk;
    }

    if (blockIdx.x == 0) {
        {
            const int e = t & 15, gg = t >> 4;   // gg in [0,16)
            float s = 0.f;
            #pragma unroll
            for (int k = 0; k < 8; ++k) s += me_part[(gg + 16 * k) * NE + e];
            me_sh[gg][e] = s;
        }
        __syncthreads();
        if (t < NE) {
            float me = 0.f;
            #pragma unroll
            for (int gg = 0; gg < 16; ++gg) me += me_sh[gg][t];
            me_tot[t] = me;
            out[OUT_CNT + t] = (float)cnt_sh[t];
        }
        __syncthreads();
        if (t == 0) {
            float la = 0.f;
            #pragma unroll
            for (int e = 0; e < NE; ++e)
                la += (me_tot[e] * (1.0f / N_TOK)) * ((float)ce_sh[e] * (1.0f / N_TOK));
            out[OUT_LAUX] = la * (float)NE;
        }
    }
}

extern "C" void kernel_launch(void* const* d_in, const int* in_sizes, int n_in,
                              void* d_out, int out_size, void* d_ws, size_t ws_size,
                              hipStream_t stream) {
    const float* x  = (const float*)d_in[0];   // [8192,4096] fp32
    const float* wg = (const float*)d_in[1];   // [16,4096] fp32
    float* out = (float*)d_out;

    char* w = (char*)d_ws;
    float* part    = (float*)w;  w += (size_t)NSEGG * N_TOK * NE * sizeof(float); // 4 MB
    int*   pr      = (int*)w;    w += TOKS * sizeof(int);         // 64 KB
    int*   hist    = (int*)w;    w += NCHUNK * NE * sizeof(int);  // 16 KB
    float* me_part = (float*)w;                                   // 8 KB

    k1_rowlane<<<(N_TOK / RPB) * NSEGG, 256, 0, stream>>>(
        (const float4*)x, (const float4*)wg, part);
    k2_route<<<N_TOK / 64, 64, 0, stream>>>(part, pr, hist, me_part, out);
    k3_place<<<TOKS / 256, 256, 0, stream>>>(pr, hist, me_part, out);
}

// Round 2
// 209.716 us; speedup vs baseline: 1.0362x; 1.0362x over previous
//
#include <hip/hip_runtime.h>
#include <math.h>

#define N_TOK 8192
#define DIM   4096
#define NE    16
#define TOKS  (2*N_TOK)        // 16384
#define NCHUNK (TOKS/64)       // 256
#define D4    (DIM/4)          // 1024 float4 per row
#define NSEGG 8                // D seg-groups (512 cols each); part combine depth
#define SLICEF4 128            // float4 per block slice (512 cols)

// d_out layout (all float32):
// [0] l_aux | [1..16384] token_pos_after | [16385..32768] token_pos_before
// [32769..32784] expert_token_count | [32785..49168] weight
#define OUT_LAUX 0
#define OUT_TPA  1
#define OUT_TPB  (1+TOKS)
#define OUT_CNT  (1+2*TOKS)
#define OUT_W    (1+2*TOKS+NE)

// K1 v3: 4-lane column groups. 1024 blocks x 256 threads.
// Block = 64 rows x one 512-col slice (g = blockIdx&7). Wave w covers rows
// w*16..w*16+15, the FULL slice. Lane = (r,c): r = lane>>2 row, c = lane&3
// col-group; group-of-4 lanes reads 4 consecutive float4s (64 B contiguous
// per row) -> each load instr touches 16 x 64-B segments instead of 64
// distinct lines (4x fewer TA/tag lookups; tests the request-divergence
// theory). Wg stays a 4-distinct-address LDS broadcast. Each wave owns
// complete rows, so the dot product finishes with a 2-stage shfl_xor and a
// contiguous float4 store of part -- no cross-wave combine, no second sync.
__global__ __launch_bounds__(256) void k1_grouped(
    const float4* __restrict__ x4, const float4* __restrict__ wg4,
    float* __restrict__ part)
{
    __shared__ float4 wgl[NE][SLICEF4];   // 32 KB  [e][slice f4]

    const int tid  = threadIdx.x;
    const int lane = tid & 63;
    const int w    = tid >> 6;            // 0..3
    const int r    = lane >> 2;           // 0..15 row within wave
    const int c    = lane & 3;            // 0..3  col group
    const int g    = blockIdx.x & 7;      // slice group (512 cols)
    const int rg   = blockIdx.x >> 3;     // row group (64 rows)

    // ---- stage Wg slice: 2048 float4, 8 per thread, coalesced ----
    #pragma unroll
    for (int i = 0; i < 8; ++i) {
        const int idx = i * 256 + tid;
        const int e = idx >> 7, cc = idx & 127;
        wgl[e][cc] = wg4[(size_t)e * D4 + g * SLICEF4 + cc];
    }
    __syncthreads();

    const int row = rg * 64 + w * 16 + r;
    const float4* xrow = x4 + (size_t)row * D4 + g * SLICEF4 + c;

    float acc[NE];
    #pragma unroll
    for (int e = 0; e < NE; ++e) acc[e] = 0.f;

    #pragma unroll
    for (int si = 0; si < 4; ++si) {
        float4 xq[8];
        #pragma unroll
        for (int k = 0; k < 8; ++k) xq[k] = xrow[4 * (si * 8 + k)];
        #pragma unroll
        for (int e = 0; e < NE; ++e) {
            float a = acc[e];
            #pragma unroll
            for (int k = 0; k < 8; ++k) {
                const float4 wv = wgl[e][c + 4 * (si * 8 + k)]; // 4-addr broadcast
                a = fmaf(xq[k].x, wv.x, a);
                a = fmaf(xq[k].y, wv.y, a);
                a = fmaf(xq[k].z, wv.z, a);
                a = fmaf(xq[k].w, wv.w, a);
            }
            acc[e] = a;
        }
    }

    // ---- finish dot products across the 4-lane group ----
    float red[NE];
    #pragma unroll
    for (int e = 0; e < NE; ++e) {
        float v = acc[e];
        v += __shfl_xor(v, 1);
        v += __shfl_xor(v, 2);
        red[e] = v;            // all 4 lanes of the group hold the sum
    }

    // lane (r,c) stores experts 4c..4c+3 as one float4:
    // part word addr = g*131072 + row*16 + 4c  -> contiguous 64 B per row
    float4 o;
    o.x = (c == 0) ? red[0] : (c == 1) ? red[4] : (c == 2) ? red[8]  : red[12];
    o.y = (c == 0) ? red[1] : (c == 1) ? red[5] : (c == 2) ? red[9]  : red[13];
    o.z = (c == 0) ? red[2] : (c == 1) ? red[6] : (c == 2) ? red[10] : red[14];
    o.w = (c == 0) ? red[3] : (c == 1) ? red[7] : (c == 2) ? red[11] : red[15];
    ((float4*)part)[(size_t)g * (N_TOK * 4) + (size_t)row * 4 + c] = o;
}

// K2: combine 8 slice partials (fixed order -> deterministic), top-2, softmax,
// weights, me partials, stable intra-chunk ranks + chunk histograms.
// 64 blocks x 128 threads, one thread per row. Wave = one 64-row chunk.
__global__ __launch_bounds__(128) void k2_route(
    const float* __restrict__ part, int* __restrict__ pr,
    int* __restrict__ hist, float* __restrict__ me_part,
    float* __restrict__ out)
{
    const int row   = blockIdx.x * 128 + threadIdx.x;
    const int lane  = threadIdx.x & 63;
    const int gwave = row >> 6;   // chunk index for top-1 half, in [0,128)

    float lg[NE];
    #pragma unroll
    for (int e = 0; e < NE; ++e) lg[e] = 0.f;
    const float4* p4 = (const float4*)part;
    #pragma unroll
    for (int s = 0; s < NSEGG; ++s) {
        const size_t base = ((size_t)s * N_TOK + row) * 4;
        #pragma unroll
        for (int q = 0; q < 4; ++q) {
            float4 t = p4[base + q];
            lg[q * 4 + 0] += t.x;
            lg[q * 4 + 1] += t.y;
            lg[q * 4 + 2] += t.z;
            lg[q * 4 + 3] += t.w;
        }
    }

    // top-2; strict > keeps lowest index on ties (matches lax.top_k)
    float m1 = -INFINITY; int i1 = 0;
    #pragma unroll
    for (int e = 0; e < NE; ++e)
        if (lg[e] > m1) { m1 = lg[e]; i1 = e; }
    float m2 = -INFINITY; int i2 = 0;
    #pragma unroll
    for (int e = 0; e < NE; ++e)
        if (e != i1 && lg[e] > m2) { m2 = lg[e]; i2 = e; }

    float ssum = 0.f, ex[NE];
    #pragma unroll
    for (int e = 0; e < NE; ++e) { ex[e] = __expf(lg[e] - m1); ssum += ex[e]; }
    const float inv = 1.f / ssum;

    const float e2v = __expf(m2 - m1);
    const float w1  = 1.f / (1.f + e2v);
    out[OUT_W + row]         = w1;
    out[OUT_W + N_TOK + row] = 1.f - w1;

    // per-wave me partial: butterfly each expert; lane e keeps expert e's sum
    float mymev = 0.f;
    #pragma unroll
    for (int e = 0; e < NE; ++e) {
        float mv = ex[e] * inv;
        mv += __shfl_xor(mv, 32); mv += __shfl_xor(mv, 16);
        mv += __shfl_xor(mv, 8);  mv += __shfl_xor(mv, 4);
        mv += __shfl_xor(mv, 2);  mv += __shfl_xor(mv, 1);
        if (lane == e) mymev = mv;
    }
    if (lane < NE) me_part[gwave * NE + lane] = mymev;

    // stable intra-chunk ranks + chunk histograms via ballot
    const unsigned long long mlt = (1ull << lane) - 1ull;
    int rk1 = 0, rk2 = 0;
    #pragma unroll
    for (int eo = 0; eo < NE; ++eo) {
        unsigned long long mA = __ballot(i1 == eo);
        unsigned long long mB = __ballot(i2 == eo);
        if (i1 == eo) rk1 = (int)__popcll(mA & mlt);
        if (i2 == eo) rk2 = (int)__popcll(mB & mlt);
        if (lane == eo) {
            hist[gwave * NE + eo]                = (int)__popcll(mA);
            hist[(NCHUNK / 2 + gwave) * NE + eo] = (int)__popcll(mB);
        }
    }
    pr[row]         = i1 | (rk1 << 8);
    pr[N_TOK + row] = i2 | (rk2 << 8);
}

// K3: 64 blocks x 256. Every block redundantly scans the 256x16 chunk
// histogram in LDS, then places its 256 tokens. Block 0 adds l_aux + counts.
__global__ __launch_bounds__(256) void k3_place(
    const int* __restrict__ pr, const int* __restrict__ hist,
    const float* __restrict__ me_part, float* __restrict__ out)
{
    __shared__ int   sh[NCHUNK][20];   // padded
    __shared__ int   cnt_sh[NE], ce_sh[NE];
    __shared__ float me_sh[16][17];
    __shared__ float me_tot[NE];

    const int t = threadIdx.x;

    int h[NE];
    {
        const int4* h4 = (const int4*)(hist + t * NE);
        int4 a = h4[0], b = h4[1], c = h4[2], d = h4[3];
        h[0]=a.x; h[1]=a.y; h[2]=a.z; h[3]=a.w;
        h[4]=b.x; h[5]=b.y; h[6]=b.z; h[7]=b.w;
        h[8]=c.x; h[9]=c.y; h[10]=c.z; h[11]=c.w;
        h[12]=d.x; h[13]=d.y; h[14]=d.z; h[15]=d.w;
    }
    #pragma unroll
    for (int e = 0; e < NE; ++e) sh[t][e] = h[e];
    __syncthreads();

    for (int off = 1; off < NCHUNK; off <<= 1) {
        int tmp[NE];
        #pragma unroll
        for (int e = 0; e < NE; ++e) tmp[e] = (t >= off) ? sh[t - off][e] : 0;
        __syncthreads();
        #pragma unroll
        for (int e = 0; e < NE; ++e) sh[t][e] += tmp[e];
        __syncthreads();
    }

    if (t == NCHUNK - 1) {
        #pragma unroll
        for (int e = 0; e < NE; ++e) cnt_sh[e] = sh[t][e];
    }
    if (t == NCHUNK / 2 - 1) {
        #pragma unroll
        for (int e = 0; e < NE; ++e) ce_sh[e] = sh[t][e];  // top-1 totals
    }

    int ex[NE];
    #pragma unroll
    for (int e = 0; e < NE; ++e) ex[e] = sh[t][e] - h[e];
    __syncthreads();
    #pragma unroll
    for (int e = 0; e < NE; ++e) sh[t][e] = ex[e];
    __syncthreads();

    int offs[NE];
    {
        int run = 0;
        #pragma unroll
        for (int e = 0; e < NE; ++e) { offs[e] = run; run += cnt_sh[e]; }
    }

    {
        const int tk = blockIdx.x * 256 + t;
        const int v  = pr[tk];
        const int e  = v & 255;
        const int rk = v >> 8;
        const int c  = tk >> 6;
        const int pos = sh[c][e] + offs[e] + rk;
        out[OUT_TPA + tk]  = (float)pos;
        out[OUT_TPB + pos] = (float)tk;
    }

    if (blockIdx.x == 0) {
        {
            const int e = t & 15, gg = t >> 4;   // gg in [0,16)
            float s = 0.f;
            #pragma unroll
            for (int k = 0; k < 8; ++k) s += me_part[(gg + 16 * k) * NE + e];
            me_sh[gg][e] = s;
        }
        __syncthreads();
        if (t < NE) {
            float me = 0.f;
            #pragma unroll
            for (int gg = 0; gg < 16; ++gg) me += me_sh[gg][t];
            me_tot[t] = me;
            out[OUT_CNT + t] = (float)cnt_sh[t];
        }
        __syncthreads();
        if (t == 0) {
            float la = 0.f;
            #pragma unroll
            for (int e = 0; e < NE; ++e)
                la += (me_tot[e] * (1.0f / N_TOK)) * ((float)ce_sh[e] * (1.0f / N_TOK));
            out[OUT_LAUX] = la * (float)NE;
        }
    }
}

extern "C" void kernel_launch(void* const* d_in, const int* in_sizes, int n_in,
                              void* d_out, int out_size, void* d_ws, size_t ws_size,
                              hipStream_t stream) {
    const float* x  = (const float*)d_in[0];   // [8192,4096] fp32
    const float* wg = (const float*)d_in[1];   // [16,4096] fp32
    float* out = (float*)d_out;

    char* w = (char*)d_ws;
    float* part    = (float*)w;  w += (size_t)NSEGG * N_TOK * NE * sizeof(float); // 4 MB
    int*   pr      = (int*)w;    w += TOKS * sizeof(int);         // 64 KB
    int*   hist    = (int*)w;    w += NCHUNK * NE * sizeof(int);  // 16 KB
    float* me_part = (float*)w;                                   // 8 KB

    k1_grouped<<<(N_TOK / 64) * NSEGG, 256, 0, stream>>>(
        (const float4*)x, (const float4*)wg, part);
    k2_route<<<N_TOK / 128, 128, 0, stream>>>(part, pr, hist, me_part, out);
    k3_place<<<TOKS / 256, 256, 0, stream>>>(pr, hist, me_part, out);
}